// Round 1
// baseline (399.651 us; speedup 1.0000x reference)
//
#include <hip/hip_runtime.h>

// PlainVoxels (VolSDF-style) fused renderer.
// One 64-lane wave per ray; lane == sample index (S = 64).
// Outputs (flat, concatenated, N = #rays):
//   [0      , 3N)   rendered_rgb     (N,3)
//   [3N     , 4N)   rendered_depth   (N,1)
//   [4N     , 7N)   rendered_normals (N,3)
//   [7N     , 8N)   acc              (N,1)
//   [8N     , 200N) sdf_grads        (N*S,3)
//   [200N   , 201N) near_out         (N,1)
//   [201N   , 202N) far_out          (N,1)

constexpr int   GRID_R   = 256;
constexpr float CELL     = 0.015f;
constexpr float ORIGIN   = -1.92f;   // -0.5 * 256 * 0.015
constexpr int   S        = 64;
constexpr float MIN_BETA = 0.015f;

__global__ __launch_bounds__(256)
void render_rays(const float* __restrict__ grid,
                 const float* __restrict__ beta_p,
                 const float* __restrict__ rays_o,
                 const float* __restrict__ rays_d,
                 const float* __restrict__ rdn,
                 const float* __restrict__ near_p,
                 const float* __restrict__ far_p,
                 float* __restrict__ out,
                 int N)
{
    const int lane = threadIdx.x & 63;
    const int ray  = blockIdx.x * (blockDim.x >> 6) + (threadIdx.x >> 6);
    if (ray >= N) return;

    const float nearv = near_p[0];
    const float farv  = far_p[0];
    const float dt    = (farv - nearv) / (float)S;
    const float t_n   = nearv + (float)lane * dt;
    const float t_mid = 0.5f * (t_n + (t_n + dt));

    const float ox = rays_o[3 * ray + 0];
    const float oy = rays_o[3 * ray + 1];
    const float oz = rays_o[3 * ray + 2];
    const float dxr = rays_d[3 * ray + 0];
    const float dyr = rays_d[3 * ray + 1];
    const float dzr = rays_d[3 * ray + 2];

    // Sample position and grid coords
    const float px = ox + t_mid * dxr;
    const float py = oy + t_mid * dyr;
    const float pz = oz + t_mid * dzr;
    const float ux = (px - ORIGIN) / CELL;
    const float uy = (py - ORIGIN) / CELL;
    const float uz = (pz - ORIGIN) / CELL;

    const bool inb = (ux >= 0.f) && (ux <= (float)(GRID_R - 1)) &&
                     (uy >= 0.f) && (uy <= (float)(GRID_R - 1)) &&
                     (uz >= 0.f) && (uz <= (float)(GRID_R - 1));

    int ix = (int)floorf(ux); ix = ix < 0 ? 0 : (ix > GRID_R - 2 ? GRID_R - 2 : ix);
    int iy = (int)floorf(uy); iy = iy < 0 ? 0 : (iy > GRID_R - 2 ? GRID_R - 2 : iy);
    int iz = (int)floorf(uz); iz = iz < 0 ? 0 : (iz > GRID_R - 2 ? GRID_R - 2 : iz);
    const float fx = ux - (float)ix;
    const float fy = uy - (float)iy;
    const float fz = uz - (float)iz;
    const float mfx = 1.f - fx, mfy = 1.f - fy, mfz = 1.f - fz;

    // Gather 8 corners x 4 channels (ch 0 = sdf, ch 1..3 = rgb; ch 4 unused)
    const float* gp = grid + (size_t)(((ix << 8) + iy) << 8 | iz) * 5;
    float v[2][2][2][4];
#pragma unroll
    for (int a = 0; a < 2; ++a)
#pragma unroll
        for (int b = 0; b < 2; ++b)
#pragma unroll
            for (int c = 0; c < 2; ++c) {
                const float* p = gp + (size_t)(((a << 8) + b) << 8 | c) * 5;
                v[a][b][c][0] = p[0];
                v[a][b][c][1] = p[1];
                v[a][b][c][2] = p[2];
                v[a][b][c][3] = p[3];
            }

    // Trilinear interp, all 4 channels; keep ch0 intermediates for the gradient
    float feat[4];
    float c00_0, c10_0, c01_0, c11_0, c0_0, c1_0;
#pragma unroll
    for (int ch = 0; ch < 4; ++ch) {
        const float c00 = v[0][0][0][ch] * mfx + v[1][0][0][ch] * fx;
        const float c10 = v[0][1][0][ch] * mfx + v[1][1][0][ch] * fx;
        const float c01 = v[0][0][1][ch] * mfx + v[1][0][1][ch] * fx;
        const float c11 = v[0][1][1][ch] * mfx + v[1][1][1][ch] * fx;
        const float c0 = c00 * mfy + c10 * fy;
        const float c1 = c01 * mfy + c11 * fy;
        feat[ch] = c0 * mfz + c1 * fz;
        if (ch == 0) { c00_0 = c00; c10_0 = c10; c01_0 = c01; c11_0 = c11; c0_0 = c0; c1_0 = c1; }
    }

    // Analytic gradient of ch0 wrt world coords (jax.grad of the trilinear):
    const float dgx_u = ((v[1][0][0][0] - v[0][0][0][0]) * mfy + (v[1][1][0][0] - v[0][1][0][0]) * fy) * mfz +
                        ((v[1][0][1][0] - v[0][0][1][0]) * mfy + (v[1][1][1][0] - v[0][1][1][0]) * fy) * fz;
    const float dgy_u = (c10_0 - c00_0) * mfz + (c11_0 - c01_0) * fz;
    const float dgz_u = c1_0 - c0_0;
    const float gx = dgx_u / CELL;
    const float gy = dgy_u / CELL;
    const float gz = dgz_u / CELL;

    // sdf_grads output (unmasked, exactly like the reference autodiff)
    {
        float* go = out + (size_t)8 * N + ((size_t)ray * S + lane) * 3;
        go[0] = gx; go[1] = gy; go[2] = gz;
    }

    // normals
    const float nrm = sqrtf(gx * gx + gy * gy + gz * gz);
    const float dn = fmaxf(nrm, 1e-12f);
    const float nx = gx / dn, ny = gy / dn, nz = gz / dn;

    // Laplace-CDF density
    const float sdf = feat[0];
    const float beta_eff = MIN_BETA + fabsf(beta_p[0]);
    const float sgn = (sdf > 0.f) ? 1.f : ((sdf < 0.f) ? -1.f : 0.f);
    float sigma = (1.f / beta_eff) * (0.5f + 0.5f * sgn * expm1f(-fabsf(sdf) / beta_eff));
    sigma = inb ? sigma : 0.f;
    const float tau = sigma * dt;

    // Exclusive prefix-sum of tau along the ray (64-lane scan)
    float incl = tau;
#pragma unroll
    for (int off = 1; off < 64; off <<= 1) {
        const float t = __shfl_up(incl, off, 64);
        if (lane >= off) incl += t;
    }
    const float T     = expf(-(incl - tau));
    const float alpha = -expm1f(-tau);
    const float w     = T * alpha;

    // Wave reductions: rgb(3), depth, normals(3), acc
    float red[8];
    red[0] = w * feat[1];
    red[1] = w * feat[2];
    red[2] = w * feat[3];
    red[3] = w * t_mid;
    red[4] = w * nx;
    red[5] = w * ny;
    red[6] = w * nz;
    red[7] = w;
#pragma unroll
    for (int off = 32; off > 0; off >>= 1) {
#pragma unroll
        for (int k = 0; k < 8; ++k)
            red[k] += __shfl_down(red[k], off, 64);
    }

    if (lane == 0) {
        const float inv_rdn = 1.f / rdn[ray];
        out[3 * ray + 0] = red[0];
        out[3 * ray + 1] = red[1];
        out[3 * ray + 2] = red[2];
        out[(size_t)3 * N + ray] = red[3] * inv_rdn;
        out[(size_t)4 * N + 3 * ray + 0] = red[4];
        out[(size_t)4 * N + 3 * ray + 1] = red[5];
        out[(size_t)4 * N + 3 * ray + 2] = red[6];
        out[(size_t)7 * N + ray] = red[7];
        out[(size_t)200 * N + ray] = nearv * inv_rdn;
        out[(size_t)201 * N + ray] = farv * inv_rdn;
    }
}

extern "C" void kernel_launch(void* const* d_in, const int* in_sizes, int n_in,
                              void* d_out, int out_size, void* d_ws, size_t ws_size,
                              hipStream_t stream) {
    const float* grid   = (const float*)d_in[0];
    const float* beta   = (const float*)d_in[1];
    const float* rays_o = (const float*)d_in[2];
    const float* rays_d = (const float*)d_in[3];
    const float* rdn    = (const float*)d_in[4];
    const float* nearp  = (const float*)d_in[5];
    const float* farp   = (const float*)d_in[6];
    float* out = (float*)d_out;

    const int N = in_sizes[2] / 3;           // rays_o is (N,3)
    const int raysPerBlock = 4;              // 256 threads = 4 waves
    const int blocks = (N + raysPerBlock - 1) / raysPerBlock;
    render_rays<<<blocks, 256, 0, stream>>>(grid, beta, rays_o, rays_d, rdn,
                                            nearp, farp, out, N);
}